// Round 12
// baseline (73.121 us; speedup 1.0000x reference)
//
#include <hip/hip_runtime.h>
#include <math.h>

typedef unsigned short u16;
typedef u16 u16x4 __attribute__((ext_vector_type(4)));
typedef u16 u16x8 __attribute__((ext_vector_type(8)));
typedef float f32x4 __attribute__((ext_vector_type(4)));
typedef float f32x16 __attribute__((ext_vector_type(16)));
typedef __bf16 bf16x8 __attribute__((ext_vector_type(8)));

#define KC 8
#define K2L 2304  // 256*9

__device__ __forceinline__ u16 f2bf_rne(float f) {
  unsigned u = __float_as_uint(f);
  u += 0x7FFFu + ((u >> 16) & 1u);
  return (u16)(u >> 16);
}
__device__ __forceinline__ float bf2f(u16 h) {
  return __uint_as_float(((unsigned)h) << 16);
}

// async global->LDS, 16B/lane; LDS dest is the WAVE-UNIFORM base (HW adds lane*16)
__device__ __forceinline__ void gload16(const u16* g, u16* l) {
  __builtin_amdgcn_global_load_lds(
      (const __attribute__((address_space(1))) unsigned*)g,
      (__attribute__((address_space(3))) unsigned*)l, 16, 0, 0);
}
__device__ __forceinline__ void vmwait0() {
  asm volatile("s_waitcnt vmcnt(0)" ::: "memory");
}

// ---- merged prep: split x, split W1, build Wc1, Wc2 ----
__device__ __forceinline__ void split4(const float* X, u16* hi, u16* lo, int i) {
  f32x4 v = ((const f32x4*)X)[i];
  u16x4 h, l;
#pragma unroll
  for (int c = 0; c < 4; ++c) {
    u16 hb = f2bf_rne(v[c]);
    h[c] = hb;
    l[c] = f2bf_rne(v[c] - bf2f(hb));
  }
  ((u16x4*)hi)[i] = h;
  ((u16x4*)lo)[i] = l;
}
__device__ __forceinline__ void wc_one(const float* coef, const float* sb, const float* sp,
                                       const float* mask, u16* W, int N, int idx) {
  int o = idx / K2L;
  int r = idx - o * K2L;
  int i = r / 9;
  int c = r - i * 9;
  int io = i * N + o;
  float m = mask[io];
  float v = (c == 0) ? m * sb[io] : m * sp[io] * coef[(size_t)io * KC + (c - 1)];
  W[idx] = f2bf_rne(v);
}

__global__ void prep_kernel(const float* __restrict__ x, const float* __restrict__ W1,
                            const float* __restrict__ coef1, const float* __restrict__ sb1,
                            const float* __restrict__ sp1, const float* __restrict__ mask1,
                            const float* __restrict__ coef2, const float* __restrict__ sb2,
                            const float* __restrict__ sp2, const float* __restrict__ mask2,
                            u16* __restrict__ xs_hi, u16* __restrict__ xs_lo,
                            u16* __restrict__ w1_hi, u16* __restrict__ w1_lo,
                            u16* __restrict__ wc1, u16* __restrict__ wc2) {
  const int b = blockIdx.x, tid = threadIdx.x;
  if (b < 4096) {
    split4(x, xs_hi, xs_lo, b * 256 + tid);
  } else if (b < 4096 + 256) {
    split4(W1, w1_hi, w1_lo, (b - 4096) * 256 + tid);
  } else if (b < 4096 + 256 + 2304) {
    wc_one(coef1, sb1, sp1, mask1, wc1, 256, (b - 4352) * 256 + tid);
  } else {
    wc_one(coef2, sb2, sp2, mask2, wc2, 128, (b - 6656) * 256 + tid);
  }
}

// ---- spline tables + divide-free expand ----
struct Spl {
  float g[12];
  float d1[11], d2[10], d3[9];
};
__device__ __forceinline__ void spl_init(const float* __restrict__ grid, Spl& sp) {
#pragma unroll
  for (int j = 0; j < 12; ++j) sp.g[j] = grid[j];
#pragma unroll
  for (int j = 0; j < 11; ++j) sp.d1[j] = 1.0f / (sp.g[j + 1] - sp.g[j]);
#pragma unroll
  for (int j = 0; j < 10; ++j) sp.d2[j] = 1.0f / (sp.g[j + 2] - sp.g[j]);
#pragma unroll
  for (int j = 0; j < 9; ++j) sp.d3[j] = 1.0f / (sp.g[j + 3] - sp.g[j]);
}
__device__ __forceinline__ void expand_one(float v, const Spl& sp, u16* dst) {
  float Bv[11];
#pragma unroll
  for (int j = 0; j < 11; ++j) Bv[j] = (v >= sp.g[j] && v < sp.g[j + 1]) ? 1.0f : 0.0f;
#pragma unroll
  for (int j = 0; j < 10; ++j)
    Bv[j] = (v - sp.g[j]) * sp.d1[j] * Bv[j] + (sp.g[j + 2] - v) * sp.d1[j + 1] * Bv[j + 1];
#pragma unroll
  for (int j = 0; j < 9; ++j)
    Bv[j] = (v - sp.g[j]) * sp.d2[j] * Bv[j] + (sp.g[j + 3] - v) * sp.d2[j + 1] * Bv[j + 1];
#pragma unroll
  for (int j = 0; j < 8; ++j)
    Bv[j] = (v - sp.g[j]) * sp.d3[j] * Bv[j] + (sp.g[j + 4] - v) * sp.d3[j + 1] * Bv[j + 1];
  dst[0] = f2bf_rne(v / (1.0f + __expf(-v)));  // silu
#pragma unroll
  for (int k = 0; k < 8; ++k) dst[1 + k] = f2bf_rne(Bv[k]);
}

// ---- 16-wave MFMA GEMM: 4 waves/SIMD (max TLP at grid 256) ----
// BM=BN=64; 16 waves = 4 quadrants (q=wid&3) x 4 K-groups (kg=wid>>2).
// BK=256 (16 K-16 slices/step; kg owns 4), 2-buf (128 KB), depth-1 prefetch.
// Per step: vmwait(0) -> s_barrier -> stage(next) -> ds_read -> 4x MFMA.
//   2-buf safety: stage writes buf cur^1 AFTER the barrier; its readers
//   (step i-1) consumed ds_reads (MFMA data-dep) before reaching the barrier.
// Staging: linear LDS dest + inverse-swizzled global SOURCE + swizzled READ
// (32 16B-slots/row, XOR row&31 -> ~2-way per 16-lane phase, free).
// Epilogue: 2-round LDS f32 reduction over kg, then fused bias+spline expand.
// NREG==3: K'=3*K regions hh/hl/lh (split-precision bf16x3, K=1024).
template <int NREG, bool EXPAND>
__global__ __launch_bounds__(1024) void gemm16w(
    const u16* __restrict__ A0, const u16* __restrict__ A1,
    const u16* __restrict__ B0, const u16* __restrict__ B1,
    const float* __restrict__ bias, const float* __restrict__ grid,
    void* __restrict__ outv, int M, int N, int K, int nsteps) {
  constexpr int ASZ = 64 * 256;     // u16 per A (or B) tile (32 KB)
  constexpr int BUF_U16 = 2 * ASZ;  // 64 KB
  __shared__ __align__(16) u16 smu[2 * BUF_U16];  // 128 KB -> 16 waves/CU

  const int tid = threadIdx.x;
  const int lane = tid & 63;
  const int wid = tid >> 6;
  const int q = wid & 3;
  const int kg = wid >> 2;

  // XCD-aware swizzle (grid sizes are multiples of 8)
  const int nb = N >> 6;
  const int nwg = (M >> 6) * nb;
  const int bid = blockIdx.x;
  const int swz = (bid & 7) * (nwg >> 3) + (bid >> 3);
  const int tm = (swz / nb) << 6;
  const int tn = (swz % nb) << 6;

  const u16* pA0 = A0 + (size_t)tm * K;
  const u16* pB0 = B0 + (size_t)tn * K;
  const u16* pA1 = (NREG == 3) ? A1 + (size_t)tm * K : nullptr;
  const u16* pB1 = (NREG == 3) ? B1 + (size_t)tn * K : nullptr;

  // staging chunk c (0..2047/tile): row=c>>5, slot=c&31; slot sources
  // k-group slot^(row&31)  (inverse-swizzle SOURCE; READ applies same XOR)
  auto srcOff = [&](int c) -> int {
    int r = c >> 5, sl = c & 31;
    return r * K + (((sl ^ (r & 31)) & 31) << 3);  // u16 units
  };
  const int s0 = srcOff(tid);
  const int s1 = srcOff(tid + 1024);

  const int wm = (q >> 1) * 32;
  const int wn = (q & 1) * 32;
  const int lr = lane & 31;
  const int khf = lane >> 5;

  // swizzled LDS read offsets (u16): row*256 + ((slot^(row&31))&31)*8,
  // slot = slice*2 + khf, slice = kg*4 + s
  int offA[4], offB[4];
#pragma unroll
  for (int s = 0; s < 4; ++s) {
    int slice = kg * 4 + s;
    int rowA = wm + lr;
    int rowB = wn + lr;
    offA[s] = rowA * 256 + ((((slice * 2 + khf) ^ (rowA & 31)) & 31) << 3);
    offB[s] = rowB * 256 + ((((slice * 2 + khf) ^ (rowB & 31)) & 31) << 3);
  }

  auto stage = [&](int buf, int step) {
    int kk;
    const u16 *Ab, *Bb;
    if constexpr (NREG == 3) {
      int reg = step >> 2;  // K=1024 -> 4 BK-256 steps per region
      kk = (step & 3) << 8;
      Ab = (reg == 2) ? pA1 : pA0;
      Bb = (reg == 1) ? pB1 : pB0;
    } else {
      kk = step << 8;
      Ab = pA0;
      Bb = pB0;
    }
    u16* sb = smu + buf * BUF_U16;
    gload16(Ab + s0 + kk, sb + wid * 512);
    gload16(Ab + s1 + kk, sb + 8192 + wid * 512);
    gload16(Bb + s0 + kk, sb + ASZ + wid * 512);
    gload16(Bb + s1 + kk, sb + ASZ + 8192 + wid * 512);
  };

  f32x16 acc0 = {}, acc1 = {};
  stage(0, 0);
  for (int i = 0; i < nsteps; ++i) {
    vmwait0();  // my 4 loads for buf[i&1] landed
    __builtin_amdgcn_sched_barrier(0);
    __builtin_amdgcn_s_barrier();  // everyone's loads landed; prior readers done
    __builtin_amdgcn_sched_barrier(0);
    if (i + 1 < nsteps) stage((i + 1) & 1, i + 1);  // overwrite-safe post-barrier

    const u16* sb = smu + (i & 1) * BUF_U16;
    bf16x8 af[4], bfr[4];
#pragma unroll
    for (int s = 0; s < 4; ++s) {
      af[s] = *(const bf16x8*)(sb + offA[s]);
      bfr[s] = *(const bf16x8*)(sb + ASZ + offB[s]);
    }
#pragma unroll
    for (int s = 0; s < 4; ++s) {
      f32x16& ac = (s & 1) ? acc1 : acc0;  // 2 chains for MFMA ILP
      ac = __builtin_amdgcn_mfma_f32_32x32x16_bf16(af[s], bfr[s], ac, 0, 0, 0);
    }
  }
  f32x16 accv = acc0 + acc1;

  // C/D layout (m74/m101): col = lane&31, row = (r&3) + 8*(r>>2) + 4*(lane>>5)
  const int rbase = 4 * khf;

  // 2-round cross-kg reduction via LDS f32 (kg2/kg3 -> kg0/kg1, then kg1 -> kg0)
  float* Fr = (float*)smu;
  __syncthreads();
  if (kg >= 2) {
#pragma unroll
    for (int r = 0; r < 16; ++r) {
      int row = wm + rbase + (r & 3) + 8 * (r >> 2);
      Fr[(kg - 2) * 4096 + row * 64 + wn + lr] = accv[r];
    }
  }
  __syncthreads();
  if (kg < 2) {
#pragma unroll
    for (int r = 0; r < 16; ++r) {
      int row = wm + rbase + (r & 3) + 8 * (r >> 2);
      accv[r] += Fr[kg * 4096 + row * 64 + wn + lr];
    }
  }
  __syncthreads();
  if (kg == 1) {
#pragma unroll
    for (int r = 0; r < 16; ++r) {
      int row = wm + rbase + (r & 3) + 8 * (r >> 2);
      Fr[row * 64 + wn + lr] = accv[r];
    }
  }
  __syncthreads();
  if (kg == 0) {
#pragma unroll
    for (int r = 0; r < 16; ++r) {
      int row = wm + rbase + (r & 3) + 8 * (r >> 2);
      accv[r] += Fr[row * 64 + wn + lr];
    }
  }

  if constexpr (EXPAND) {
    Spl sp;
    spl_init(grid, sp);
    __syncthreads();  // Fr reads done before F-tile overwrite
    u16* Fl = smu;
    if (kg == 0) {
      int col = wn + lr;
      float bv = bias ? bias[tn + col] : 0.0f;
#pragma unroll
      for (int r = 0; r < 16; ++r) {
        int row = wm + rbase + (r & 3) + 8 * (r >> 2);
        expand_one(accv[r] + bv, sp, Fl + (size_t)row * (64 * 9) + col * 9);
      }
    }
    __syncthreads();
    // coalesced copy-out: 64 x 576 bf16 in 16B chunks, all 1024 threads
    u16* Fout = (u16*)outv;
    const size_t fstride = (size_t)N * 9;
#pragma unroll
    for (int ch = tid; ch < 4608; ch += 1024) {  // 64 rows x 72 chunks
      int r = ch / 72, o = ch - r * 72;
      *(u16x8*)(Fout + (size_t)(tm + r) * fstride + (size_t)tn * 9 + o * 8) =
          *(const u16x8*)(Fl + (size_t)ch * 8);
    }
  } else {
    if (kg == 0) {
      float* Cp = (float*)outv;
      const int cbase = tn + wn + lr;
#pragma unroll
      for (int r = 0; r < 16; ++r) {
        int row = tm + wm + rbase + (r & 3) + 8 * (r >> 2);
        Cp[(size_t)row * N + cbase] = accv[r];
      }
    }
  }
}

extern "C" void kernel_launch(void* const* d_in, const int* in_sizes, int n_in,
                              void* d_out, int out_size, void* d_ws, size_t ws_size,
                              hipStream_t stream) {
  (void)in_sizes; (void)n_in; (void)out_size; (void)ws_size;
  const float* x     = (const float*)d_in[0];   // 4096x1024
  const float* W1    = (const float*)d_in[1];   // 256x1024
  const float* b1    = (const float*)d_in[2];   // 256
  const float* grid1 = (const float*)d_in[3];   // 256x12 (rows identical)
  const float* coef1 = (const float*)d_in[4];   // 256x256x8
  const float* sb1   = (const float*)d_in[5];
  const float* sp1   = (const float*)d_in[6];
  const float* mask1 = (const float*)d_in[7];
  const float* grid2 = (const float*)d_in[8];
  const float* coef2 = (const float*)d_in[9];   // 256x128x8
  const float* sb2   = (const float*)d_in[10];
  const float* sp2   = (const float*)d_in[11];
  const float* mask2 = (const float*)d_in[12];
  float* outp = (float*)d_out;

  char* ws = (char*)d_ws;
  size_t off = 0;
  auto alloc = [&](size_t bytes) {
    char* p = ws + off;
    off += (bytes + 255) & ~(size_t)255;
    return (void*)p;
  };
  u16* xs_hi  = (u16*)alloc((size_t)4096 * 1024 * 2);
  u16* xs_lo  = (u16*)alloc((size_t)4096 * 1024 * 2);
  u16* w1_hi  = (u16*)alloc((size_t)256 * 1024 * 2);
  u16* w1_lo  = (u16*)alloc((size_t)256 * 1024 * 2);
  u16* wc1    = (u16*)alloc((size_t)256 * K2L * 2);
  u16* wc2    = (u16*)alloc((size_t)128 * K2L * 2);
  u16* F1     = (u16*)alloc((size_t)4096 * K2L * 2);
  u16* F2     = (u16*)alloc((size_t)4096 * K2L * 2);

  // merged prep
  prep_kernel<<<7808, 256, 0, stream>>>(x, W1, coef1, sb1, sp1, mask1,
                                        coef2, sb2, sp2, mask2,
                                        xs_hi, xs_lo, w1_hi, w1_lo, wc1, wc2);

  // L1: F1 = expand(x @ W1^T + b1); bf16x3 as K'=3072; 12 steps; 256 blocks x 16 waves
  gemm16w<3, true><<<256, 1024, 0, stream>>>(
      xs_hi, xs_lo, w1_hi, w1_lo, b1, grid1, F1, 4096, 256, 1024, 12);

  // L2: F2 = expand(F1 @ Wc1^T); K=2304; 9 steps; 256 blocks x 16 waves
  gemm16w<1, true><<<256, 1024, 0, stream>>>(
      F1, nullptr, wc1, nullptr, nullptr, grid2, F2, 4096, 256, 2304, 9);

  // L3: out = F2 @ Wc2^T; K=2304, N=128; 9 steps; 128 blocks x 16 waves
  gemm16w<1, false><<<128, 1024, 0, stream>>>(
      F2, nullptr, wc2, nullptr, nullptr, nullptr, outp, 4096, 128, 2304, 9);
}